// Round 10
// baseline (373.337 us; speedup 1.0000x reference)
//
#include <hip/hip_runtime.h>
#include <hip/hip_bf16.h>
#include <cstdint>
#include <cstddef>

// LRU forward: y = Re(C·scan(Λ, x·Bᵀ)) + D·x
// Split-bf16 MFMA GEMMs (3-term: hi·hi + hi·lo + lo·hi, ~1e-5 rel err)
// + 3-phase chunked diagonal complex scan (fwd & bwd in one pass each).
//
// R10 vs R9 (322.6 µs): scan occupancy fix via CH 64->16, NCH 256->1024.
//  - scan3 was 1 block/CU = 1 wave/SIMD on a 192 MB kernel (suspected
//    ~80 µs). Now 1024 blocks = 4/CU, 16 waves/CU. Body unchanged (R5
//    float2 loads + packed u32 stores).
//  - scan1: 1024 blocks, 32 waves/CU.
//  - scan2: two-pass per lane (16 chunks/lane), A = Pc^16 by squarings.
//  - carries 8 MB -> workspace re-layout, peak 204 MiB (R3 proved >=232).
// GEMMs frozen (933 TF eff; MfmaUtil 38.5%; conflicts 0 across R5/R6/R9).

#define L_DIM 16384
#define N_DIM 512
#define H_DIM 512
#define CH    16
#define NCH   1024   // L_DIM / CH

typedef short s16x8 __attribute__((ext_vector_type(8)));   // 8 x bf16 bits
typedef float f32x4 __attribute__((ext_vector_type(4)));

// float -> (hi, lo) bf16 pair, stored as raw ushort bits
__device__ inline void split2(float v, unsigned short* hi, unsigned short* lo) {
    __hip_bfloat16 h = __float2bfloat16(v);
    float hv = __bfloat162float(h);
    __hip_bfloat16 l = __float2bfloat16(v - hv);
    *hi = *(unsigned short*)&h;
    *lo = *(unsigned short*)&l;
}

// two adjacent-n floats -> packed u32 hi-pair + u32 lo-pair (coalesced 4B/lane)
__device__ inline void split_store2(float a, float b,
                                    unsigned short* hp, unsigned short* lp) {
    unsigned short ha, la, hb, lb;
    split2(a, &ha, &la);
    split2(b, &hb, &lb);
    *(unsigned int*)hp = (unsigned int)ha | ((unsigned int)hb << 16);
    *(unsigned int*)lp = (unsigned int)la | ((unsigned int)lb << 16);
}

__device__ inline void gload16(const void* g, void* l) {
    __builtin_amdgcn_global_load_lds(
        (const __attribute__((address_space(1))) void*)g,
        (__attribute__((address_space(3))) void*)l, 16, 0, 0);
}

__device__ inline void lam_of(int n, const float* nu_log, const float* th_log,
                              float& lr, float& li) {
    float nu = expf(nu_log[n]);
    float th = expf(th_log[n]);
    float em = expf(-nu);
    lr = em * cosf(th);
    li = em * sinf(th);
}

// ---------------------------------------------------------------------------
// Convert: x -> (x_hi,x_lo); B -> gamma*(Bre|Bim) hi/lo (1024x512 K-major);
// C -> [C1re | -C1im | C2re | -C2im] hi/lo (512x2048 K-major).
// ---------------------------------------------------------------------------
__global__ void k_convert(const float* __restrict__ x,
                          const float* __restrict__ Bre, const float* __restrict__ Bim,
                          const float* __restrict__ Cre, const float* __restrict__ Cim,
                          const float* __restrict__ Cre2, const float* __restrict__ Cim2,
                          const float* __restrict__ nu_log, const float* __restrict__ th_log,
                          unsigned short* __restrict__ xh, unsigned short* __restrict__ xl,
                          unsigned short* __restrict__ bnh, unsigned short* __restrict__ bnl,
                          unsigned short* __restrict__ cch, unsigned short* __restrict__ ccl)
{
    const int XU = L_DIM * H_DIM / 4;       // 2097152
    const int BU = 2 * N_DIM * H_DIM / 4;   // 131072
    const int CU = 4 * H_DIM * N_DIM / 4;   // 262144
    const int TOT = XU + BU + CU;
    for (int u = blockIdx.x * blockDim.x + threadIdx.x; u < TOT;
         u += gridDim.x * blockDim.x) {
        if (u < XU) {
            int i0 = u * 4;
            float4 v = *(const float4*)(x + i0);
            split2(v.x, xh + i0 + 0, xl + i0 + 0);
            split2(v.y, xh + i0 + 1, xl + i0 + 1);
            split2(v.z, xh + i0 + 2, xl + i0 + 2);
            split2(v.w, xh + i0 + 3, xl + i0 + 3);
        } else if (u < XU + BU) {
            int i0 = (u - XU) * 4;
            int row = i0 >> 9;             // 0..1023 (re rows then im rows)
            int h0  = i0 & 511;
            int n   = row & (N_DIM - 1);
            const float* src = (row < N_DIM) ? Bre : Bim;
            float nu = expf(nu_log[n]);
            float g  = sqrtf(fmaxf(0.f, 1.f - expf(-2.f * nu)));
            float4 v = *(const float4*)(src + n * H_DIM + h0);
            split2(g * v.x, bnh + i0 + 0, bnl + i0 + 0);
            split2(g * v.y, bnh + i0 + 1, bnl + i0 + 1);
            split2(g * v.z, bnh + i0 + 2, bnl + i0 + 2);
            split2(g * v.w, bnh + i0 + 3, bnl + i0 + 3);
        } else {
            int i0 = (u - XU - BU) * 4;
            int h   = i0 >> 11;            // 0..511
            int k0  = i0 & 2047;
            int mat = k0 >> 9;             // 0..3
            int c0  = k0 & 511;
            const float* src = (mat == 0) ? Cre : (mat == 1) ? Cim
                             : (mat == 2) ? Cre2 : Cim2;
            float s = (mat & 1) ? -1.f : 1.f;   // fold minus on im parts
            float4 v = *(const float4*)(src + h * N_DIM + c0);
            split2(s * v.x, cch + i0 + 0, ccl + i0 + 0);
            split2(s * v.y, cch + i0 + 1, ccl + i0 + 1);
            split2(s * v.z, cch + i0 + 2, ccl + i0 + 2);
            split2(s * v.w, cch + i0 + 3, ccl + i0 + 3);
        }
    }
}

// ---------------------------------------------------------------------------
// Split-bf16 MFMA GEMM, both operands K-major (A: MxK rows, B: NCxK rows).
// 128x128 tile, BK=32, 4 waves in a 2x2 grid (64x64 output per wave).
// Wave w stages operand tile w of {Ah,Al,Bh,Bl} via global_load_lds
// (8 x 1KB issues, linear LDS dest). Slot XOR-swizzle ((row&15)>>1)&3 on
// the GLOBAL source (rule #21) + same involution on the ds_read side.
// T1: chunked XCD swizzle. R5/R6/R9 counters: ~112 µs, MfmaUtil 38-40%,
// conflicts 0, 933 TF effective (2-barrier ceiling). FROZEN.
// ---------------------------------------------------------------------------
template<bool EPI, int K, int NC>
__global__ __launch_bounds__(256, 2)
void k_gemm(const unsigned short* __restrict__ Ah, const unsigned short* __restrict__ Al,
            const unsigned short* __restrict__ Bh, const unsigned short* __restrict__ Bl,
            float* __restrict__ Out,
            const float* __restrict__ Dv, const float* __restrict__ Xres)
{
    __shared__ unsigned short smem[4 * 128 * 32];   // Ah|Al|Bh|Bl tiles, 32 KiB
    const int tid  = threadIdx.x;
    const int wave = tid >> 6;
    const int lane = tid & 63;

    // T1 chunked XCD swizzle (bijective; nwg % 8 == 0 for both GEMMs)
    constexpr int GX = NC / 128;               // col-blocks (8 for g1, 4 for g2)
    const int nwg  = GX * (L_DIM / 128);
    const int flat = blockIdx.y * GX + blockIdx.x;
    const int q    = nwg >> 3;
    const int nf   = (flat & 7) * q + (flat >> 3);
    const int brow = (nf / GX) * 128;
    const int bcol = (nf % GX) * 128;

    const int wr   = wave >> 1;            // 0..1: row half of wave grid
    const int wc   = wave & 1;             // 0..1: col half

    // wave w stages source w (select chain, not runtime-indexed array)
    const unsigned short* gsrc = (wave == 0) ? Ah : (wave == 1) ? Al
                               : (wave == 2) ? Bh : Bl;
    const int rowbase = (wave < 2) ? brow : bcol;
    // per-lane staging source: row = rowbase + j*16 + (lane>>2),
    // col slot = (lane&3) ^ ((lane>>3)&3)  [= slot ^ ((row&15)>>1)&3]
    const unsigned short* gp = gsrc
        + (size_t)(rowbase + (lane >> 2)) * K
        + (((lane & 3) ^ ((lane >> 3) & 3)) << 3);
    unsigned short* lbase = smem + wave * 4096;

    f32x4 acc[4][4];
    #pragma unroll
    for (int i = 0; i < 4; ++i) {
        #pragma unroll
        for (int j = 0; j < 4; ++j) acc[i][j] = (f32x4){0.f, 0.f, 0.f, 0.f};
    }

    const int r    = lane & 15;
    const int kg   = lane >> 4;
    const int slot = ((kg ^ ((r >> 1) & 3)) << 3);  // element offset in row

    const unsigned short* sAh = smem;
    const unsigned short* sAl = smem + 4096;
    const unsigned short* sBh = smem + 8192;
    const unsigned short* sBl = smem + 12288;

    const int nK = K >> 5;
    for (int kt = 0; kt < nK; ++kt) {
        const unsigned short* g = gp + kt * 32;
        #pragma unroll
        for (int j = 0; j < 8; ++j)
            gload16(g + (size_t)j * 16 * K, lbase + j * 512);
        __syncthreads();

        s16x8 ah[4], al[4];
        #pragma unroll
        for (int mi = 0; mi < 4; ++mi) {
            int row = wr * 64 + mi * 16 + r;
            ah[mi] = *(const s16x8*)(sAh + row * 32 + slot);
            al[mi] = *(const s16x8*)(sAl + row * 32 + slot);
        }
        #pragma unroll
        for (int ni = 0; ni < 4; ++ni) {
            int rowb = wc * 64 + ni * 16 + r;
            s16x8 bh = *(const s16x8*)(sBh + rowb * 32 + slot);
            s16x8 bl = *(const s16x8*)(sBl + rowb * 32 + slot);
            #pragma unroll
            for (int mi = 0; mi < 4; ++mi) {
                acc[mi][ni] = __builtin_amdgcn_mfma_f32_16x16x32_bf16(ah[mi], bh, acc[mi][ni], 0, 0, 0);
                acc[mi][ni] = __builtin_amdgcn_mfma_f32_16x16x32_bf16(al[mi], bh, acc[mi][ni], 0, 0, 0);
                acc[mi][ni] = __builtin_amdgcn_mfma_f32_16x16x32_bf16(ah[mi], bl, acc[mi][ni], 0, 0, 0);
            }
        }
        __syncthreads();
    }

    // epilogue: C/D mapping col=lane&15, row=(lane>>4)*4+j  [m89/m91]
    #pragma unroll
    for (int mi = 0; mi < 4; ++mi) {
        #pragma unroll
        for (int ni = 0; ni < 4; ++ni) {
            #pragma unroll
            for (int j = 0; j < 4; ++j) {
                int row = brow + wr * 64 + mi * 16 + kg * 4 + j;
                int col = bcol + wc * 64 + ni * 16 + r;
                float v = acc[mi][ni][j];
                if (EPI) v += Dv[col] * Xres[(size_t)row * H_DIM + col];
                Out[(size_t)row * NC + col] = v;
            }
        }
    }
}

// ---------------------------------------------------------------------------
// Scan phase 1: per chunk (CH=16 rows), local fwd-end carry and bwd-start
// carry (single forward pass: s_f = Λ s_f + u ;  s_b += Λ^j u).
// 1024 blocks x 512 thr -> 4 blocks/CU, 32 waves/CU.
// ---------------------------------------------------------------------------
__global__ void k_scan1(const float* __restrict__ Bu,
                        const float* __restrict__ nu_log, const float* __restrict__ th_log,
                        float* __restrict__ cfr, float* __restrict__ cfi,
                        float* __restrict__ cbr, float* __restrict__ cbi)
{
    const int n = threadIdx.x;
    const int c = blockIdx.x;
    float lr, li; lam_of(n, nu_log, th_log, lr, li);
    float sfr = 0.f, sfi = 0.f, sbr = 0.f, sbi = 0.f, pr = 1.f, pi = 0.f;
    const float* base = Bu + (size_t)c * CH * 1024;
    for (int l = 0; l < CH; ++l) {
        float ur = base[l * 1024 + n];
        float ui = base[l * 1024 + 512 + n];
        float tr = lr * sfr - li * sfi + ur;
        float ti = lr * sfi + li * sfr + ui;
        sfr = tr; sfi = ti;
        sbr += pr * ur - pi * ui;
        sbi += pr * ui + pi * ur;
        float t2 = lr * pr - li * pi;
        pi = lr * pi + li * pr;
        pr = t2;
    }
    int o = c * N_DIM + n;
    cfr[o] = sfr; cfi[o] = sfi; cbr[o] = sbr; cbi[o] = sbi;
}

// ---------------------------------------------------------------------------
// Scan phase 2 (R10): wave-parallel cross-chunk combine, two-pass.
// 1024 wave-tasks = (n in [0,512)) x (dir in {fwd,bwd}); one 64-lane wave
// per task, 16 chunks per lane (NCH=1024).
//   pass 1: lane total I over its 16 chunks; lane transform A = Pc^16.
//   6-step shfl_up inclusive scan over (A, I); L = exclusive lane carry.
//   pass 2: re-read v[j], write carry-in, S = v + Pc*S (running).
// Contract unchanged: carry arrays rewritten in place as per-chunk carry-IN.
// ---------------------------------------------------------------------------
__global__ void k_scan2(const float* __restrict__ nu_log, const float* __restrict__ th_log,
                        float* __restrict__ cfr, float* __restrict__ cfi,
                        float* __restrict__ cbr, float* __restrict__ cbi)
{
    const int wave_id = blockIdx.x * (blockDim.x >> 6) + (threadIdx.x >> 6);
    const int lane    = threadIdx.x & 63;
    const int dir     = wave_id >> 9;          // 0 = fwd, 1 = bwd
    const int n       = wave_id & 511;

    float nu = expf(nu_log[n]);
    float th = expf(th_log[n]);
    float mg = expf(-(float)CH * nu);          // |Λ|^CH
    float ph = (float)CH * th;                 // CH·θ
    float Pcr = mg * cosf(ph);
    float Pci = mg * sinf(ph);

    float* Vr = dir ? cbr : cfr;
    float* Vi = dir ? cbi : cfi;

    const int CPL = NCH / 64;                  // 16 chunks per lane
    const int p0  = CPL * lane;

    // pass 1: lane-inclusive total I over chunks p0..p0+15
    float Ir = 0.f, Ii = 0.f;
    for (int j = 0; j < CPL; ++j) {
        int pos = p0 + j;
        int c   = dir ? (NCH - 1 - pos) : pos;
        int o   = c * N_DIM + n;
        float vr = Vr[o], vi = Vi[o];
        float tr = vr + Pcr * Ir - Pci * Ii;
        float ti = vi + Pcr * Ii + Pci * Ir;
        Ir = tr; Ii = ti;
    }
    // lane transform A = Pc^16 by 4 squarings
    float Ar = Pcr, Ai = Pci;
    #pragma unroll
    for (int s = 0; s < 4; ++s) {
        float t = Ar * Ar - Ai * Ai;
        Ai = 2.f * Ar * Ai;
        Ar = t;
    }

    // inclusive wave scan over (A, I): cur∘prev -> I = A*I_prev + I, A = A*A_prev
    #pragma unroll
    for (int s = 1; s < 64; s <<= 1) {
        float Irp = __shfl_up(Ir, (unsigned)s, 64);
        float Iip = __shfl_up(Ii, (unsigned)s, 64);
        float Arp = __shfl_up(Ar, (unsigned)s, 64);
        float Aip = __shfl_up(Ai, (unsigned)s, 64);
        if (lane >= s) {
            float nIr = Ar * Irp - Ai * Iip + Ir;
            float nIi = Ar * Iip + Ai * Irp + Ii;
            Ir = nIr; Ii = nIi;
            float nAr = Ar * Arp - Ai * Aip;
            float nAi = Ar * Aip + Ai * Arp;
            Ar = nAr; Ai = nAi;
        }
    }
    // exclusive lane carry L = inclusive of lane-1 (lane 0 -> 0)
    float Sr = __shfl_up(Ir, 1u, 64);
    float Si = __shfl_up(Ii, 1u, 64);
    if (lane == 0) { Sr = 0.f; Si = 0.f; }

    // pass 2: running carry-in; read v before overwriting (same thread)
    for (int j = 0; j < CPL; ++j) {
        int pos = p0 + j;
        int c   = dir ? (NCH - 1 - pos) : pos;
        int o   = c * N_DIM + n;
        float vr = Vr[o], vi = Vi[o];
        Vr[o] = Sr; Vi[o] = Si;
        float tr = vr + Pcr * Sr - Pci * Si;
        float ti = vi + Pcr * Si + Pci * Sr;
        Sr = tr; Si = ti;
    }
}

// ---------------------------------------------------------------------------
// Scan phase 3: apply carries, write states as split-bf16 into S (L x 2048):
// cols [0,512)=f_re, [512,1024)=f_im, [1024,1536)=b_re, [1536,2048)=b_im.
// R5 body (float2 loads, 2n/thread, packed u32 stores); CH=16 ->
// 1024 blocks x 256 thr = 4 blocks/CU, 16 waves/CU (was 1 wave/SIMD).
// ---------------------------------------------------------------------------
__global__ void k_scan3(const float* __restrict__ Bu,
                        const float* __restrict__ nu_log, const float* __restrict__ th_log,
                        const float* __restrict__ cfr, const float* __restrict__ cfi,
                        const float* __restrict__ cbr, const float* __restrict__ cbi,
                        unsigned short* __restrict__ Sh, unsigned short* __restrict__ Sl)
{
    const int t  = threadIdx.x;            // 0..255
    const int c  = blockIdx.x;
    const int n0 = 2 * t;
    const int n1 = 2 * t + 1;
    float lr0, li0, lr1, li1;
    lam_of(n0, nu_log, th_log, lr0, li0);
    lam_of(n1, nu_log, th_log, lr1, li1);
    const float* base = Bu + (size_t)c * CH * 1024;
    unsigned short* shb = Sh + (size_t)c * CH * 2048;
    unsigned short* slb = Sl + (size_t)c * CH * 2048;
    const int o0 = c * N_DIM + n0;
    const int o1 = c * N_DIM + n1;

    float sr0 = cfr[o0], si0 = cfi[o0];
    float sr1 = cfr[o1], si1 = cfi[o1];
    for (int l = 0; l < CH; ++l) {
        float2 ur = *(const float2*)(base + l * 1024 + n0);
        float2 ui = *(const float2*)(base + l * 1024 + 512 + n0);
        float tr0 = lr0 * sr0 - li0 * si0 + ur.x;
        float ti0 = lr0 * si0 + li0 * sr0 + ui.x;
        sr0 = tr0; si0 = ti0;
        float tr1 = lr1 * sr1 - li1 * si1 + ur.y;
        float ti1 = lr1 * si1 + li1 * sr1 + ui.y;
        sr1 = tr1; si1 = ti1;
        split_store2(sr0, sr1, shb + l * 2048 + n0,       slb + l * 2048 + n0);
        split_store2(si0, si1, shb + l * 2048 + 512 + n0, slb + l * 2048 + 512 + n0);
    }
    sr0 = cbr[o0]; si0 = cbi[o0];
    sr1 = cbr[o1]; si1 = cbi[o1];
    for (int l = CH - 1; l >= 0; --l) {
        float2 ur = *(const float2*)(base + l * 1024 + n0);
        float2 ui = *(const float2*)(base + l * 1024 + 512 + n0);
        float tr0 = lr0 * sr0 - li0 * si0 + ur.x;
        float ti0 = lr0 * si0 + li0 * sr0 + ui.x;
        sr0 = tr0; si0 = ti0;
        float tr1 = lr1 * sr1 - li1 * si1 + ur.y;
        float ti1 = lr1 * si1 + li1 * sr1 + ui.y;
        sr1 = tr1; si1 = ti1;
        split_store2(sr0, sr1, shb + l * 2048 + 1024 + n0, slb + l * 2048 + 1024 + n0);
        split_store2(si0, si1, shb + l * 2048 + 1536 + n0, slb + l * 2048 + 1536 + n0);
    }
}

// ---------------------------------------------------------------------------
extern "C" void kernel_launch(void* const* d_in, const int* in_sizes, int n_in,
                              void* d_out, int out_size, void* d_ws, size_t ws_size,
                              hipStream_t stream)
{
    const float* x      = (const float*)d_in[0];
    const float* th_log = (const float*)d_in[1];
    const float* nu_log = (const float*)d_in[2];
    const float* Bre    = (const float*)d_in[3];
    const float* Bim    = (const float*)d_in[4];
    const float* Cre    = (const float*)d_in[5];
    const float* Cim    = (const float*)d_in[6];
    const float* Cre2   = (const float*)d_in[7];
    const float* Cim2   = (const float*)d_in[8];
    const float* Dv     = (const float*)d_in[9];
    float* y = (float*)d_out;

    // Workspace layout with lifetime overlap (peak 204 MiB; R3 proved >=232):
    //   [0,64M)        Bu   f32 (L x 1024)        GEMM1 -> scan1/scan3
    //   [64M,66M)      cch  (512 x 2048)          convert -> GEMM2
    //   [66M,68M)      ccl
    //   [68M,76M)      carries (4 x 2 MiB, NCH=1024)  scan1 -> scan2 -> scan3
    //   [76M,140M)     Sh   (L x 2048)            scan3 -> GEMM2
    //   [140M,204M)    Sl
    //   [76M,110M)     xh/xl/bnh/bnl (temps)      convert -> GEMM1 (dead
    //                  before scan3 writes Sh over this region)
    char* ws = (char*)d_ws;
    const size_t MB = 1048576;
    float*          Bu  = (float*)         (ws + 0);
    unsigned short* cch = (unsigned short*)(ws + 64 * MB);
    unsigned short* ccl = (unsigned short*)(ws + 66 * MB);
    float*          cfr = (float*)         (ws + 68 * MB);
    float*          cfi = cfr + NCH * N_DIM;
    float*          cbr = cfi + NCH * N_DIM;
    float*          cbi = cbr + NCH * N_DIM;
    unsigned short* Sh  = (unsigned short*)(ws + 76 * MB);
    unsigned short* Sl  = (unsigned short*)(ws + 140 * MB);
    unsigned short* xh  = (unsigned short*)(ws + 76 * MB);   // aliases Sh (ok)
    unsigned short* xl  = (unsigned short*)(ws + 92 * MB);
    unsigned short* bnh = (unsigned short*)(ws + 108 * MB);
    unsigned short* bnl = (unsigned short*)(ws + 109 * MB);
    if (ws_size < (size_t)204 * MB) return;  // guard: need 204 MiB scratch

    k_convert<<<dim3(2048), dim3(256), 0, stream>>>(
        x, Bre, Bim, Cre, Cim, Cre2, Cim2, nu_log, th_log,
        xh, xl, bnh, bnl, cch, ccl);

    k_gemm<false, 512, 1024><<<dim3(8, 128), dim3(256), 0, stream>>>(
        xh, xl, bnh, bnl, Bu, nullptr, nullptr);

    k_scan1<<<dim3(NCH), dim3(512), 0, stream>>>(
        Bu, nu_log, th_log, cfr, cfi, cbr, cbi);

    k_scan2<<<dim3(256), dim3(256), 0, stream>>>(
        nu_log, th_log, cfr, cfi, cbr, cbi);

    k_scan3<<<dim3(NCH), dim3(256), 0, stream>>>(
        Bu, nu_log, th_log, cfr, cfi, cbr, cbi, Sh, Sl);

    k_gemm<true, 2048, 512><<<dim3(4, 128), dim3(256), 0, stream>>>(
        Sh, Sl, cch, ccl, y, Dv, x);
}

// Round 11
// 288.453 us; speedup vs baseline: 1.2943x; 1.2943x over previous
//
#include <hip/hip_runtime.h>
#include <hip/hip_bf16.h>
#include <cstdint>
#include <cstddef>

// LRU forward: y = Re(C·scan(Λ, x·Bᵀ)) + D·x
// R11 vs R10 (373.3; best=R9 322.6):
//  - REVERT all scans to R9 exact (CH=64/NCH=256). R10's CH=16 was −50 µs
//    regression; occupancy was not the scans' limiter (2nd failed theory).
//  - NEW: states stored as plain bf16 (drop Sl). GEMM2 becomes 2-term
//    Ah·Bh + Ah·Bl (C-side still split -> B error ~2^-17; state-side ~2^-9,
//    below the measured 3e-3 scan-association noise floor). GEMM2 FLOPs
//    103->68.7 GF; scan3 writes 128->64 MB; workspace peak 134 MiB.
// GEMM1 unchanged (3-term split-bf16, proven).

#define L_DIM 16384
#define N_DIM 512
#define H_DIM 512
#define CH    64
#define NCH   256   // L_DIM / CH

typedef short s16x8 __attribute__((ext_vector_type(8)));   // 8 x bf16 bits
typedef float f32x4 __attribute__((ext_vector_type(4)));

// float -> (hi, lo) bf16 pair, stored as raw ushort bits
__device__ inline void split2(float v, unsigned short* hi, unsigned short* lo) {
    __hip_bfloat16 h = __float2bfloat16(v);
    float hv = __bfloat162float(h);
    __hip_bfloat16 l = __float2bfloat16(v - hv);
    *hi = *(unsigned short*)&h;
    *lo = *(unsigned short*)&l;
}

// pack two floats' bf16 into one u32 (lo half = a, hi half = b)
__device__ inline unsigned int pack_bf16_2(float a, float b) {
    __hip_bfloat16 ha = __float2bfloat16(a);
    __hip_bfloat16 hb = __float2bfloat16(b);
    return (unsigned int)*(unsigned short*)&ha
         | ((unsigned int)*(unsigned short*)&hb << 16);
}

__device__ inline void gload16(const void* g, void* l) {
    __builtin_amdgcn_global_load_lds(
        (const __attribute__((address_space(1))) void*)g,
        (__attribute__((address_space(3))) void*)l, 16, 0, 0);
}

__device__ inline void lam_of(int n, const float* nu_log, const float* th_log,
                              float& lr, float& li) {
    float nu = expf(nu_log[n]);
    float th = expf(th_log[n]);
    float em = expf(-nu);
    lr = em * cosf(th);
    li = em * sinf(th);
}

// ---------------------------------------------------------------------------
// Convert: x -> (x_hi,x_lo); B -> gamma*(Bre|Bim) hi/lo (1024x512 K-major);
// C -> [C1re | -C1im | C2re | -C2im] hi/lo (512x2048 K-major).
// ---------------------------------------------------------------------------
__global__ void k_convert(const float* __restrict__ x,
                          const float* __restrict__ Bre, const float* __restrict__ Bim,
                          const float* __restrict__ Cre, const float* __restrict__ Cim,
                          const float* __restrict__ Cre2, const float* __restrict__ Cim2,
                          const float* __restrict__ nu_log, const float* __restrict__ th_log,
                          unsigned short* __restrict__ xh, unsigned short* __restrict__ xl,
                          unsigned short* __restrict__ bnh, unsigned short* __restrict__ bnl,
                          unsigned short* __restrict__ cch, unsigned short* __restrict__ ccl)
{
    const int XU = L_DIM * H_DIM / 4;       // 2097152
    const int BU = 2 * N_DIM * H_DIM / 4;   // 131072
    const int CU = 4 * H_DIM * N_DIM / 4;   // 262144
    const int TOT = XU + BU + CU;
    for (int u = blockIdx.x * blockDim.x + threadIdx.x; u < TOT;
         u += gridDim.x * blockDim.x) {
        if (u < XU) {
            int i0 = u * 4;
            float4 v = *(const float4*)(x + i0);
            split2(v.x, xh + i0 + 0, xl + i0 + 0);
            split2(v.y, xh + i0 + 1, xl + i0 + 1);
            split2(v.z, xh + i0 + 2, xl + i0 + 2);
            split2(v.w, xh + i0 + 3, xl + i0 + 3);
        } else if (u < XU + BU) {
            int i0 = (u - XU) * 4;
            int row = i0 >> 9;             // 0..1023 (re rows then im rows)
            int h0  = i0 & 511;
            int n   = row & (N_DIM - 1);
            const float* src = (row < N_DIM) ? Bre : Bim;
            float nu = expf(nu_log[n]);
            float g  = sqrtf(fmaxf(0.f, 1.f - expf(-2.f * nu)));
            float4 v = *(const float4*)(src + n * H_DIM + h0);
            split2(g * v.x, bnh + i0 + 0, bnl + i0 + 0);
            split2(g * v.y, bnh + i0 + 1, bnl + i0 + 1);
            split2(g * v.z, bnh + i0 + 2, bnl + i0 + 2);
            split2(g * v.w, bnh + i0 + 3, bnl + i0 + 3);
        } else {
            int i0 = (u - XU - BU) * 4;
            int h   = i0 >> 11;            // 0..511
            int k0  = i0 & 2047;
            int mat = k0 >> 9;             // 0..3
            int c0  = k0 & 511;
            const float* src = (mat == 0) ? Cre : (mat == 1) ? Cim
                             : (mat == 2) ? Cre2 : Cim2;
            float s = (mat & 1) ? -1.f : 1.f;   // fold minus on im parts
            float4 v = *(const float4*)(src + h * N_DIM + c0);
            split2(s * v.x, cch + i0 + 0, ccl + i0 + 0);
            split2(s * v.y, cch + i0 + 1, ccl + i0 + 1);
            split2(s * v.z, cch + i0 + 2, ccl + i0 + 2);
            split2(s * v.w, cch + i0 + 3, ccl + i0 + 3);
        }
    }
}

// ---------------------------------------------------------------------------
// GEMM1 (3-term split-bf16), K-major both operands. 128x128 tile, BK=32,
// 4 waves 2x2 (64x64/wave). Wave w stages tile w of {Ah,Al,Bh,Bl} via
// global_load_lds. Slot XOR-swizzle on global source + ds_read (rule #21).
// T1 chunked XCD swizzle. FROZEN (933 TF eff, conflicts 0, R5/R6/R9/R10).
// ---------------------------------------------------------------------------
template<bool EPI, int K, int NC>
__global__ __launch_bounds__(256, 2)
void k_gemm(const unsigned short* __restrict__ Ah, const unsigned short* __restrict__ Al,
            const unsigned short* __restrict__ Bh, const unsigned short* __restrict__ Bl,
            float* __restrict__ Out,
            const float* __restrict__ Dv, const float* __restrict__ Xres)
{
    __shared__ unsigned short smem[4 * 128 * 32];   // Ah|Al|Bh|Bl tiles, 32 KiB
    const int tid  = threadIdx.x;
    const int wave = tid >> 6;
    const int lane = tid & 63;

    constexpr int GX = NC / 128;
    const int nwg  = GX * (L_DIM / 128);
    const int flat = blockIdx.y * GX + blockIdx.x;
    const int q    = nwg >> 3;
    const int nf   = (flat & 7) * q + (flat >> 3);
    const int brow = (nf / GX) * 128;
    const int bcol = (nf % GX) * 128;

    const int wr   = wave >> 1;
    const int wc   = wave & 1;

    const unsigned short* gsrc = (wave == 0) ? Ah : (wave == 1) ? Al
                               : (wave == 2) ? Bh : Bl;
    const int rowbase = (wave < 2) ? brow : bcol;
    const unsigned short* gp = gsrc
        + (size_t)(rowbase + (lane >> 2)) * K
        + (((lane & 3) ^ ((lane >> 3) & 3)) << 3);
    unsigned short* lbase = smem + wave * 4096;

    f32x4 acc[4][4];
    #pragma unroll
    for (int i = 0; i < 4; ++i) {
        #pragma unroll
        for (int j = 0; j < 4; ++j) acc[i][j] = (f32x4){0.f, 0.f, 0.f, 0.f};
    }

    const int r    = lane & 15;
    const int kg   = lane >> 4;
    const int slot = ((kg ^ ((r >> 1) & 3)) << 3);

    const unsigned short* sAh = smem;
    const unsigned short* sAl = smem + 4096;
    const unsigned short* sBh = smem + 8192;
    const unsigned short* sBl = smem + 12288;

    const int nK = K >> 5;
    for (int kt = 0; kt < nK; ++kt) {
        const unsigned short* g = gp + kt * 32;
        #pragma unroll
        for (int j = 0; j < 8; ++j)
            gload16(g + (size_t)j * 16 * K, lbase + j * 512);
        __syncthreads();

        s16x8 ah[4], al[4];
        #pragma unroll
        for (int mi = 0; mi < 4; ++mi) {
            int row = wr * 64 + mi * 16 + r;
            ah[mi] = *(const s16x8*)(sAh + row * 32 + slot);
            al[mi] = *(const s16x8*)(sAl + row * 32 + slot);
        }
        #pragma unroll
        for (int ni = 0; ni < 4; ++ni) {
            int rowb = wc * 64 + ni * 16 + r;
            s16x8 bh = *(const s16x8*)(sBh + rowb * 32 + slot);
            s16x8 bl = *(const s16x8*)(sBl + rowb * 32 + slot);
            #pragma unroll
            for (int mi = 0; mi < 4; ++mi) {
                acc[mi][ni] = __builtin_amdgcn_mfma_f32_16x16x32_bf16(ah[mi], bh, acc[mi][ni], 0, 0, 0);
                acc[mi][ni] = __builtin_amdgcn_mfma_f32_16x16x32_bf16(al[mi], bh, acc[mi][ni], 0, 0, 0);
                acc[mi][ni] = __builtin_amdgcn_mfma_f32_16x16x32_bf16(ah[mi], bl, acc[mi][ni], 0, 0, 0);
            }
        }
        __syncthreads();
    }

    #pragma unroll
    for (int mi = 0; mi < 4; ++mi) {
        #pragma unroll
        for (int ni = 0; ni < 4; ++ni) {
            #pragma unroll
            for (int j = 0; j < 4; ++j) {
                int row = brow + wr * 64 + mi * 16 + kg * 4 + j;
                int col = bcol + wc * 64 + ni * 16 + r;
                float v = acc[mi][ni][j];
                if (EPI) v += Dv[col] * Xres[(size_t)row * H_DIM + col];
                Out[(size_t)row * NC + col] = v;
            }
        }
    }
}

// ---------------------------------------------------------------------------
// GEMM2 (R11): 2-term, A = states plain bf16 (L x 2048), B = cch/ccl
// (512 x 2048 split). acc += Ah*Bh + Ah*Bl  [= Ah*(Bh+Bl), C-side ~2^-17].
// Same 128x128/BK=32/2x2-wave structure; waves 0-2 stage {A, Bh, Bl}.
// ---------------------------------------------------------------------------
__global__ __launch_bounds__(256, 2)
void k_gemm2(const unsigned short* __restrict__ Ap,
             const unsigned short* __restrict__ Bh, const unsigned short* __restrict__ Bl,
             float* __restrict__ Out,
             const float* __restrict__ Dv, const float* __restrict__ Xres)
{
    constexpr int K = 2048, NC = 512;
    __shared__ unsigned short smem[3 * 128 * 32];   // A|Bh|Bl tiles, 24 KiB
    const int tid  = threadIdx.x;
    const int wave = tid >> 6;
    const int lane = tid & 63;

    constexpr int GX = NC / 128;               // 4
    const int nwg  = GX * (L_DIM / 128);       // 512
    const int flat = blockIdx.y * GX + blockIdx.x;
    const int q    = nwg >> 3;
    const int nf   = (flat & 7) * q + (flat >> 3);
    const int brow = (nf / GX) * 128;
    const int bcol = (nf % GX) * 128;

    const int wr   = wave >> 1;
    const int wc   = wave & 1;

    const unsigned short* gsrc = (wave == 0) ? Ap : (wave == 1) ? Bh : Bl;
    const int rowbase = (wave == 0) ? brow : bcol;
    const unsigned short* gp = gsrc
        + (size_t)(rowbase + (lane >> 2)) * K
        + (((lane & 3) ^ ((lane >> 3) & 3)) << 3);
    unsigned short* lbase = smem + wave * 4096;

    f32x4 acc[4][4];
    #pragma unroll
    for (int i = 0; i < 4; ++i) {
        #pragma unroll
        for (int j = 0; j < 4; ++j) acc[i][j] = (f32x4){0.f, 0.f, 0.f, 0.f};
    }

    const int r    = lane & 15;
    const int kg   = lane >> 4;
    const int slot = ((kg ^ ((r >> 1) & 3)) << 3);

    const unsigned short* sA  = smem;
    const unsigned short* sBh = smem + 4096;
    const unsigned short* sBl = smem + 8192;

    const int nK = K >> 5;   // 64
    for (int kt = 0; kt < nK; ++kt) {
        if (wave < 3) {
            const unsigned short* g = gp + kt * 32;
            #pragma unroll
            for (int j = 0; j < 8; ++j)
                gload16(g + (size_t)j * 16 * K, lbase + j * 512);
        }
        __syncthreads();

        s16x8 ah[4];
        #pragma unroll
        for (int mi = 0; mi < 4; ++mi) {
            int row = wr * 64 + mi * 16 + r;
            ah[mi] = *(const s16x8*)(sA + row * 32 + slot);
        }
        #pragma unroll
        for (int ni = 0; ni < 4; ++ni) {
            int rowb = wc * 64 + ni * 16 + r;
            s16x8 bh = *(const s16x8*)(sBh + rowb * 32 + slot);
            s16x8 bl = *(const s16x8*)(sBl + rowb * 32 + slot);
            #pragma unroll
            for (int mi = 0; mi < 4; ++mi) {
                acc[mi][ni] = __builtin_amdgcn_mfma_f32_16x16x32_bf16(ah[mi], bh, acc[mi][ni], 0, 0, 0);
                acc[mi][ni] = __builtin_amdgcn_mfma_f32_16x16x32_bf16(ah[mi], bl, acc[mi][ni], 0, 0, 0);
            }
        }
        __syncthreads();
    }

    #pragma unroll
    for (int mi = 0; mi < 4; ++mi) {
        #pragma unroll
        for (int ni = 0; ni < 4; ++ni) {
            #pragma unroll
            for (int j = 0; j < 4; ++j) {
                int row = brow + wr * 64 + mi * 16 + kg * 4 + j;
                int col = bcol + wc * 64 + ni * 16 + r;
                float v = acc[mi][ni][j]
                        + Dv[col] * Xres[(size_t)row * H_DIM + col];
                Out[(size_t)row * NC + col] = v;
            }
        }
    }
}

// ---------------------------------------------------------------------------
// Scan phase 1 (R9 exact): per chunk, local fwd-end & bwd-start carries.
// ---------------------------------------------------------------------------
__global__ void k_scan1(const float* __restrict__ Bu,
                        const float* __restrict__ nu_log, const float* __restrict__ th_log,
                        float* __restrict__ cfr, float* __restrict__ cfi,
                        float* __restrict__ cbr, float* __restrict__ cbi)
{
    const int n = threadIdx.x;
    const int c = blockIdx.x;
    float lr, li; lam_of(n, nu_log, th_log, lr, li);
    float sfr = 0.f, sfi = 0.f, sbr = 0.f, sbi = 0.f, pr = 1.f, pi = 0.f;
    const float* base = Bu + (size_t)c * CH * 1024;
    for (int l = 0; l < CH; ++l) {
        float ur = base[l * 1024 + n];
        float ui = base[l * 1024 + 512 + n];
        float tr = lr * sfr - li * sfi + ur;
        float ti = lr * sfi + li * sfr + ui;
        sfr = tr; sfi = ti;
        sbr += pr * ur - pi * ui;
        sbi += pr * ui + pi * ur;
        float t2 = lr * pr - li * pi;
        pi = lr * pi + li * pr;
        pr = t2;
    }
    int o = c * N_DIM + n;
    cfr[o] = sfr; cfi[o] = sfi; cbr[o] = sbr; cbi[o] = sbi;
}

// ---------------------------------------------------------------------------
// Scan phase 2 (R9 exact): wave-parallel cross-chunk combine; 1024 waves,
// 4 chunks/lane, 6-step shfl_up inclusive scan over (A, I) pairs.
// ---------------------------------------------------------------------------
__global__ void k_scan2(const float* __restrict__ nu_log, const float* __restrict__ th_log,
                        float* __restrict__ cfr, float* __restrict__ cfi,
                        float* __restrict__ cbr, float* __restrict__ cbi)
{
    const int wave_id = blockIdx.x * (blockDim.x >> 6) + (threadIdx.x >> 6);
    const int lane    = threadIdx.x & 63;
    const int dir     = wave_id >> 9;          // 0 = fwd, 1 = bwd
    const int n       = wave_id & 511;

    float nu = expf(nu_log[n]);
    float th = expf(th_log[n]);
    float mg = expf(-(float)CH * nu);          // |Λ|^CH
    float ph = (float)CH * th;                 // CH·θ
    float Pcr = mg * cosf(ph);
    float Pci = mg * sinf(ph);

    float* Vr = dir ? cbr : cfr;
    float* Vi = dir ? cbi : cfi;

    int c0 = 4 * lane;
    int idx[4];
    #pragma unroll
    for (int j = 0; j < 4; ++j) {
        int pos = c0 + j;
        int c   = dir ? (NCH - 1 - pos) : pos;
        idx[j] = c * N_DIM + n;
    }
    float vr[4], vi[4];
    #pragma unroll
    for (int j = 0; j < 4; ++j) { vr[j] = Vr[idx[j]]; vi[j] = Vi[idx[j]]; }

    float p_r[4], p_i[4];
    p_r[0] = 0.f; p_i[0] = 0.f;
    #pragma unroll
    for (int j = 0; j < 3; ++j) {
        p_r[j + 1] = vr[j] + Pcr * p_r[j] - Pci * p_i[j];
        p_i[j + 1] = vi[j] + Pcr * p_i[j] + Pci * p_r[j];
    }
    float Ir = vr[3] + Pcr * p_r[3] - Pci * p_i[3];
    float Ii = vi[3] + Pcr * p_i[3] + Pci * p_r[3];
    float P2r = Pcr * Pcr - Pci * Pci,  P2i = 2.f * Pcr * Pci;
    float P3r = P2r * Pcr - P2i * Pci,  P3i = P2r * Pci + P2i * Pcr;
    float Ar  = P3r * Pcr - P3i * Pci,  Ai  = P3r * Pci + P3i * Pcr;  // Pc^4

    #pragma unroll
    for (int s = 1; s < 64; s <<= 1) {
        float Irp = __shfl_up(Ir, (unsigned)s, 64);
        float Iip = __shfl_up(Ii, (unsigned)s, 64);
        float Arp = __shfl_up(Ar, (unsigned)s, 64);
        float Aip = __shfl_up(Ai, (unsigned)s, 64);
        if (lane >= s) {
            float nIr = Ar * Irp - Ai * Iip + Ir;
            float nIi = Ar * Iip + Ai * Irp + Ii;
            Ir = nIr; Ii = nIi;
            float nAr = Ar * Arp - Ai * Aip;
            float nAi = Ar * Aip + Ai * Arp;
            Ar = nAr; Ai = nAi;
        }
    }
    float Lr = __shfl_up(Ir, 1u, 64);
    float Li = __shfl_up(Ii, 1u, 64);
    if (lane == 0) { Lr = 0.f; Li = 0.f; }

    float Pjr = 1.f, Pji = 0.f;
    #pragma unroll
    for (int j = 0; j < 4; ++j) {
        float cr = p_r[j] + Pjr * Lr - Pji * Li;
        float ci = p_i[j] + Pjr * Li + Pji * Lr;
        Vr[idx[j]] = cr;
        Vi[idx[j]] = ci;
        if (j < 3) {
            float t = Pjr * Pcr - Pji * Pci;
            Pji = Pjr * Pci + Pji * Pcr;
            Pjr = t;
        }
    }
}

// ---------------------------------------------------------------------------
// Scan phase 3 (R9 body, Sl dropped): apply carries, write states as plain
// bf16 into Sh (L x 2048): [f_re | f_im | b_re | b_im]. 256 thr x 2n;
// float2 loads, packed-u32 bf16-pair stores.
// ---------------------------------------------------------------------------
__global__ void k_scan3(const float* __restrict__ Bu,
                        const float* __restrict__ nu_log, const float* __restrict__ th_log,
                        const float* __restrict__ cfr, const float* __restrict__ cfi,
                        const float* __restrict__ cbr, const float* __restrict__ cbi,
                        unsigned short* __restrict__ Sh)
{
    const int t  = threadIdx.x;            // 0..255
    const int c  = blockIdx.x;
    const int n0 = 2 * t;
    const int n1 = 2 * t + 1;
    float lr0, li0, lr1, li1;
    lam_of(n0, nu_log, th_log, lr0, li0);
    lam_of(n1, nu_log, th_log, lr1, li1);
    const float* base = Bu + (size_t)c * CH * 1024;
    unsigned short* shb = Sh + (size_t)c * CH * 2048;
    const int o0 = c * N_DIM + n0;
    const int o1 = c * N_DIM + n1;

    float sr0 = cfr[o0], si0 = cfi[o0];
    float sr1 = cfr[o1], si1 = cfi[o1];
    for (int l = 0; l < CH; ++l) {
        float2 ur = *(const float2*)(base + l * 1024 + n0);
        float2 ui = *(const float2*)(base + l * 1024 + 512 + n0);
        float tr0 = lr0 * sr0 - li0 * si0 + ur.x;
        float ti0 = lr0 * si0 + li0 * sr0 + ui.x;
        sr0 = tr0; si0 = ti0;
        float tr1 = lr1 * sr1 - li1 * si1 + ur.y;
        float ti1 = lr1 * si1 + li1 * sr1 + ui.y;
        sr1 = tr1; si1 = ti1;
        *(unsigned int*)(shb + l * 2048 + n0)       = pack_bf16_2(sr0, sr1);
        *(unsigned int*)(shb + l * 2048 + 512 + n0) = pack_bf16_2(si0, si1);
    }
    sr0 = cbr[o0]; si0 = cbi[o0];
    sr1 = cbr[o1]; si1 = cbi[o1];
    for (int l = CH - 1; l >= 0; --l) {
        float2 ur = *(const float2*)(base + l * 1024 + n0);
        float2 ui = *(const float2*)(base + l * 1024 + 512 + n0);
        float tr0 = lr0 * sr0 - li0 * si0 + ur.x;
        float ti0 = lr0 * si0 + li0 * sr0 + ui.x;
        sr0 = tr0; si0 = ti0;
        float tr1 = lr1 * sr1 - li1 * si1 + ur.y;
        float ti1 = lr1 * si1 + li1 * sr1 + ui.y;
        sr1 = tr1; si1 = ti1;
        *(unsigned int*)(shb + l * 2048 + 1024 + n0) = pack_bf16_2(sr0, sr1);
        *(unsigned int*)(shb + l * 2048 + 1536 + n0) = pack_bf16_2(si0, si1);
    }
}

// ---------------------------------------------------------------------------
extern "C" void kernel_launch(void* const* d_in, const int* in_sizes, int n_in,
                              void* d_out, int out_size, void* d_ws, size_t ws_size,
                              hipStream_t stream)
{
    const float* x      = (const float*)d_in[0];
    const float* th_log = (const float*)d_in[1];
    const float* nu_log = (const float*)d_in[2];
    const float* Bre    = (const float*)d_in[3];
    const float* Bim    = (const float*)d_in[4];
    const float* Cre    = (const float*)d_in[5];
    const float* Cim    = (const float*)d_in[6];
    const float* Cre2   = (const float*)d_in[7];
    const float* Cim2   = (const float*)d_in[8];
    const float* Dv     = (const float*)d_in[9];
    float* y = (float*)d_out;

    // Workspace (peak 134 MiB; lifetime overlap proven R3/R5/R6/R9):
    //   [0,64M)    Bu f32 (L x 1024)   GEMM1 -> scan1/scan3
    //   [64M,66M)  cch                 convert -> GEMM2
    //   [66M,68M)  ccl
    //   [68M,70M)  carries (4 x 512KB) scan1 -> scan2 -> scan3
    //   [70M,134M) Sh bf16 (L x 2048)  scan3 -> GEMM2
    //   [70M,104M) xh/xl/bnh/bnl temps convert -> GEMM1 (dead before scan3)
    char* ws = (char*)d_ws;
    const size_t MB = 1048576;
    float*          Bu  = (float*)         (ws + 0);
    unsigned short* cch = (unsigned short*)(ws + 64 * MB);
    unsigned short* ccl = (unsigned short*)(ws + 66 * MB);
    float*          cfr = (float*)         (ws + 68 * MB);
    float*          cfi = cfr + NCH * N_DIM;
    float*          cbr = cfi + NCH * N_DIM;
    float*          cbi = cbr + NCH * N_DIM;
    unsigned short* Sh  = (unsigned short*)(ws + 70 * MB);
    unsigned short* xh  = (unsigned short*)(ws + 70 * MB);   // aliases Sh (ok)
    unsigned short* xl  = (unsigned short*)(ws + 86 * MB);
    unsigned short* bnh = (unsigned short*)(ws + 102 * MB);
    unsigned short* bnl = (unsigned short*)(ws + 103 * MB);
    if (ws_size < (size_t)134 * MB) return;  // guard: need 134 MiB scratch

    k_convert<<<dim3(2048), dim3(256), 0, stream>>>(
        x, Bre, Bim, Cre, Cim, Cre2, Cim2, nu_log, th_log,
        xh, xl, bnh, bnl, cch, ccl);

    k_gemm<false, 512, 1024><<<dim3(8, 128), dim3(256), 0, stream>>>(
        xh, xl, bnh, bnl, Bu, nullptr, nullptr);

    k_scan1<<<dim3(NCH), dim3(512), 0, stream>>>(
        Bu, nu_log, th_log, cfr, cfi, cbr, cbi);

    k_scan2<<<dim3(256), dim3(256), 0, stream>>>(
        nu_log, th_log, cfr, cfi, cbr, cbi);

    k_scan3<<<dim3(NCH), dim3(256), 0, stream>>>(
        Bu, nu_log, th_log, cfr, cfi, cbr, cbi, Sh);

    k_gemm2<<<dim3(4, 128), dim3(256), 0, stream>>>(
        Sh, cch, ccl, y, Dv, x);
}